// Round 4
// baseline (351.447 us; speedup 1.0000x reference)
//
#include <hip/hip_runtime.h>
#include <math.h>

#define NROWS 262144
#define NPART 1024
#define MAXTIES 256
#define H1BINS 4096
#define CAP 65536
typedef unsigned int uint;

struct Accum {
  double kl_part[NPART];
  double tls_part[NPART];
  double clean_part[NPART];
  double corr_part[NPART];
  double cnt_part[NPART];
  uint cand_cnt;
  uint pad;
};

// ============ parallel bin-select: 256 threads each hold count h; find first t with
// inclusive-prefix >= k. Unique winner: incl >= k && excl < k (h==0 can't win).
__device__ __forceinline__ void select256(uint h, uint k, uint* wsum, uint* binrem) {
  int t = threadIdx.x, l = t & 63, w = t >> 6;
  uint incl = h;
#pragma unroll
  for (int d = 1; d < 64; d <<= 1) {
    uint o = __shfl_up(incl, d, 64);
    incl += (l >= d) ? o : 0u;
  }
  if (l == 63) wsum[w] = incl;
  __syncthreads();
  uint off = 0;
#pragma unroll
  for (int i = 0; i < 3; i++) off += (i < w) ? wsum[i] : 0u;
  incl += off;
  uint excl = incl - h;
  if (incl >= k && excl < k) { binrem[0] = (uint)t; binrem[1] = k - excl; }
  __syncthreads();
}

// Find smallest bin with cumsum >= k in the 4096-bin histogram (256 chunks of 16).
__device__ __forceinline__ void sel4096(const uint* __restrict__ hist, uint k,
                                        uint* wsum, uint* binrem,
                                        uint* out_bin, uint* out_rem) {
  int t = threadIdx.x;
  const uint4* hp = reinterpret_cast<const uint4*>(hist + t * 16);
  uint4 v0 = hp[0], v1 = hp[1], v2 = hp[2], v3 = hp[3];
  uint h = v0.x + v0.y + v0.z + v0.w + v1.x + v1.y + v1.z + v1.w
         + v2.x + v2.y + v2.z + v2.w + v3.x + v3.y + v3.z + v3.w;
  select256(h, k, wsum, binrem);
  uint chunk = binrem[0], rem1 = binrem[1];
  __syncthreads();
  uint h2 = (t < 16) ? hist[chunk * 16 + t] : 0u;
  select256(h2, rem1, wsum, binrem);
  *out_bin = chunk * 16 + binrem[0];
  *out_rem = binrem[1];
  __syncthreads();
}

__device__ __forceinline__ uint calc_nr(int ep) {
  double fr = 0.005 * (double)ep; if (fr > 0.5) fr = 0.5;
  double rr = 1.0 - fr;           if (rr < 0.5) rr = 0.5;
  return (uint)(rr * (double)NROWS);
}

__device__ __forceinline__ double block_sum_d(double v, double* s) {
#pragma unroll
  for (int msk = 1; msk < 64; msk <<= 1) v += __shfl_xor(v, msk, 64);
  int wid = threadIdx.x >> 6, lane = threadIdx.x & 63;
  __syncthreads();
  if (lane == 0) s[wid] = v;
  __syncthreads();
  return s[0] + s[1] + s[2] + s[3];
}

// ============ K1: per-row stats, 16 lanes/row, 8 rows/wave.
// Both row-groups processed in ONE merged body: 4 independent shuffle-reduce chains
// (2 groups x 2 heads) interleaved at source level to hide DS-op latency.
// exp values are recomputed (not stored) to keep VGPR <= ~70.
__global__ __launch_bounds__(256) void k_rows(
    const float* __restrict__ y1, const float* __restrict__ y2,
    const int* __restrict__ tgt,
    float* __restrict__ tl, float* __restrict__ corr, unsigned char* __restrict__ mask,
    Accum* __restrict__ acc) {
  const int tid = threadIdx.x;
  const int w = tid >> 6, l = tid & 63;
  const int wb = blockIdx.x * 32 + w * 8;          // this wave's 8 rows
  const int seg = l & 15, base = seg * 8, sub = l >> 4;

  const float4* q1 = reinterpret_cast<const float4*>(y1 + (size_t)wb * 128) + 2 * l;
  const float4* q2 = reinterpret_cast<const float4*>(y2 + (size_t)wb * 128) + 2 * l;
  // all 8 vector loads issued before any compute
  float4 a00 = q1[0],   a01 = q1[1];
  float4 a10 = q1[128], a11 = q1[129];
  float4 b00 = q2[0],   b01 = q2[1];
  float4 b10 = q2[128], b11 = q2[129];
  int row[2]; row[0] = wb + sub; row[1] = wb + 4 + sub;
  int tg[2];  tg[0] = tgt[row[0]]; tg[1] = tgt[row[1]];
  // prefetch target-class logits early (t known immediately; avoids dependent
  // epilogue gathers). Only seg==0 lanes consume them.
  float y1t[2], y2t[2];
  if (seg == 0) {
#pragma unroll
    for (int g = 0; g < 2; g++) {
      y1t[g] = y1[(size_t)row[g] * 128 + tg[g]];
      y2t[g] = y2[(size_t)row[g] * 128 + tg[g]];
    }
  }

  float av[2][8] = {{a00.x,a00.y,a00.z,a00.w,a01.x,a01.y,a01.z,a01.w},
                    {a10.x,a10.y,a10.z,a10.w,a11.x,a11.y,a11.z,a11.w}};
  float bv[2][8] = {{b00.x,b00.y,b00.z,b00.w,b01.x,b01.y,b01.z,b01.w},
                    {b10.x,b10.y,b10.z,b10.w,b11.x,b11.y,b11.z,b11.w}};

  // ---- per-lane max/argmax (first occurrence), both groups, both heads ----
  float m1[2], m2[2]; int i1[2], i2[2];
#pragma unroll
  for (int g = 0; g < 2; g++) {
    m1[g] = av[g][0]; i1[g] = 0;
    m2[g] = bv[g][0]; i2[g] = 0;
#pragma unroll
    for (int j = 1; j < 8; j++) {
      if (av[g][j] > m1[g]) { m1[g] = av[g][j]; i1[g] = j; }
      if (bv[g][j] > m2[g]) { m2[g] = bv[g][j]; i2[g] = j; }
    }
    i1[g] += base; i2[g] += base;
  }
  // ---- 4 interleaved cross-lane argmax chains ----
#pragma unroll
  for (int msk = 1; msk < 16; msk <<= 1) {
#pragma unroll
    for (int g = 0; g < 2; g++) {
      float om1 = __shfl_xor(m1[g], msk, 64); int oi1 = __shfl_xor(i1[g], msk, 64);
      float om2 = __shfl_xor(m2[g], msk, 64); int oi2 = __shfl_xor(i2[g], msk, 64);
      if (om1 > m1[g] || (om1 == m1[g] && oi1 < i1[g])) { m1[g] = om1; i1[g] = oi1; }
      if (om2 > m2[g] || (om2 == m2[g] && oi2 < i2[g])) { m2[g] = om2; i2[g] = oi2; }
    }
  }
  // ---- z sums (exp recomputed later; not stored) ----
  float z1[2] = {0.f, 0.f}, z2[2] = {0.f, 0.f};
#pragma unroll
  for (int g = 0; g < 2; g++) {
#pragma unroll
    for (int j = 0; j < 8; j++) {
      z1[g] += __expf(av[g][j] - m1[g]);
      z2[g] += __expf(bv[g][j] - m2[g]);
    }
  }
#pragma unroll
  for (int msk = 1; msk < 16; msk <<= 1) {
#pragma unroll
    for (int g = 0; g < 2; g++) {
      z1[g] += __shfl_xor(z1[g], msk, 64);
      z2[g] += __shfl_xor(z2[g], msk, 64);
    }
  }
  float logZ1[2], logZ2[2], dZ[2], rz1[2], rz2[2];
#pragma unroll
  for (int g = 0; g < 2; g++) {
    logZ1[g] = m1[g] + __logf(z1[g]);
    logZ2[g] = m2[g] + __logf(z2[g]);
    rz1[g] = 1.f / z1[g]; rz2[g] = 1.f / z2[g];
    dZ[g] = logZ1[g] - logZ2[g];
  }
  // ---- symmetric KL contribution, 2 interleaved chains ----
  float kl[2] = {0.f, 0.f};
#pragma unroll
  for (int g = 0; g < 2; g++) {
#pragma unroll
    for (int j = 0; j < 8; j++) {
      float p1 = __expf(av[g][j] - m1[g]) * rz1[g];
      float p2 = __expf(bv[g][j] - m2[g]) * rz2[g];
      kl[g] += (p1 - p2) * ((av[g][j] - bv[g][j]) - dZ[g]);
    }
  }
#pragma unroll
  for (int msk = 1; msk < 16; msk <<= 1) {
#pragma unroll
    for (int g = 0; g < 2; g++) kl[g] += __shfl_xor(kl[g], msk, 64);
  }

  __shared__ float skl[32], stt[32];
  if (seg == 0) {
#pragma unroll
    for (int g = 0; g < 2; g++) {
      float y2pl = y2[(size_t)row[g] * 128 + i1[g]];   // cache-hot dependent gather
      float total = (logZ1[g] - y1t[g]) + (logZ2[g] - y2t[g]);   // >= 0
      float prod = rz1[g] * rz2[g];                              // conf1*conf2
      float corrv = sqrtf(prod) * ((logZ1[g] - m1[g]) + (logZ2[g] - y2pl));
      tl[row[g]] = total;
      corr[row[g]] = corrv;
      mask[row[g]] = (unsigned char)((i1[g] == i2[g]) && (prod > 0.5f));
      skl[w * 8 + g * 4 + sub] = kl[g];
      stt[w * 8 + g * 4 + sub] = total;
    }
  }
  __syncthreads();
  if (tid < 32) {
    double sk = (double)skl[tid], st = (double)stt[tid];
#pragma unroll
    for (int msk = 1; msk < 32; msk <<= 1) {
      sk += __shfl_xor(sk, msk, 64);
      st += __shfl_xor(st, msk, 64);
    }
    if (tid == 0) {
      int slot = blockIdx.x & (NPART - 1);
      atomicAdd(&acc->kl_part[slot], sk);
      atomicAdd(&acc->tls_part[slot], st);
    }
  }
}

// ============ K2: level-1 histogram (top 12 bits), LDS-privatized, uint4 reads ============
__global__ __launch_bounds__(1024) void k_hist1(const float* __restrict__ tl,
                                                uint* __restrict__ hist1) {
  __shared__ uint h[H1BINS];
  int tid = threadIdx.x;
  for (int j = tid; j < H1BINS; j += 1024) h[j] = 0;
  __syncthreads();
  int i = (blockIdx.x * 1024 + tid) * 4;
  uint4 kk = *reinterpret_cast<const uint4*>(reinterpret_cast<const uint*>(tl) + i);
  atomicAdd(&h[kk.x >> 20], 1u);
  atomicAdd(&h[kk.y >> 20], 1u);
  atomicAdd(&h[kk.z >> 20], 1u);
  atomicAdd(&h[kk.w >> 20], 1u);
  __syncthreads();
  for (int j = tid; j < H1BINS; j += 1024) {
    uint v = h[j];
    if (v) atomicAdd(&hist1[j], v);
  }
}

// ============ K3: single-pass partition by 12-bit prefix.
// prefix < B1 -> clean sum; prefix > B1 -> masked corr sum; prefix == B1 -> candidate.
// Candidate append is block-aggregated: LDS staging + ONE global atomic per block.
__global__ __launch_bounds__(256) void k_part(
    const float* __restrict__ tl, const float* __restrict__ corr,
    const unsigned char* __restrict__ mask, const uint* __restrict__ hist1,
    const int* __restrict__ ep, Accum* __restrict__ acc, uint2* __restrict__ cand) {
  __shared__ uint wsum[4], binrem[2];
  __shared__ double sred[4];
  __shared__ uint lcnt, lbase;
  __shared__ uint2 lcand[1024];                 // worst case: whole block in bin B1
  uint B1, needed;
  sel4096(hist1, calc_nr(ep[0]), wsum, binrem, &B1, &needed);
  (void)needed;
  if (threadIdx.x == 0) lcnt = 0;
  __syncthreads();

  int idx = blockIdx.x * 256 + threadIdx.x;
  int i = idx * 4;
  uint4 kk = *reinterpret_cast<const uint4*>(reinterpret_cast<const uint*>(tl) + i);
  float4 cv = *reinterpret_cast<const float4*>(corr + i);
  uint mb = reinterpret_cast<const uint*>(mask)[idx];
  uint keys[4] = {kk.x, kk.y, kk.z, kk.w};
  float cvs[4] = {cv.x, cv.y, cv.z, cv.w};
  double cl = 0.0, co = 0.0, cn = 0.0;
#pragma unroll
  for (int j = 0; j < 4; j++) {
    uint pre = keys[j] >> 20;
    if (pre < B1) {
      cl += (double)__uint_as_float(keys[j]);
    } else if (pre == B1) {
      uint p = atomicAdd(&lcnt, 1u);            // LDS atomic — cheap
      lcand[p] = make_uint2(keys[j], (uint)(i + j));
    } else if ((mb >> (8 * j)) & 0xFFu) {
      co += (double)cvs[j]; cn += 1.0;
    }
  }
  __syncthreads();
  uint n = lcnt;
  if (threadIdx.x == 0 && n) lbase = atomicAdd(&acc->cand_cnt, n);
  __syncthreads();
  if (n) {
    uint b = lbase;
    for (uint j = threadIdx.x; j < n; j += 256)
      if (b + j < CAP) cand[b + j] = lcand[j];
  }
  double scl = block_sum_d(cl, sred);
  double sco = block_sum_d(co, sred);
  double scn = block_sum_d(cn, sred);
  if (threadIdx.x == 0) {
    acc->clean_part[blockIdx.x] = scl;
    acc->corr_part[blockIdx.x]  = sco;
    acc->cnt_part[blockIdx.x]   = scn;
  }
}

// ============ K4: finalize — exact select among candidates (low 20 bits via three
// LDS-histogram passes: bits 19:12, 11:4, 3:0), tie-by-row-index, combine partials.
__global__ __launch_bounds__(256) void k_final(
    const float* __restrict__ corr, const unsigned char* __restrict__ mask,
    const uint* __restrict__ hist1, const uint2* __restrict__ cand,
    Accum* __restrict__ acc, const int* __restrict__ ep, float* __restrict__ out) {
  __shared__ uint wsum[4], binrem[2];
  __shared__ double sred[4];
  __shared__ uint hA[256];
  __shared__ uint tie_idx[MAXTIES];
  __shared__ uint tie_cnt;
  int t = threadIdx.x;

  double kl = 0, tls = 0, cl = 0, co = 0, cn = 0;
  for (int i = t; i < NPART; i += 256) {
    kl  += acc->kl_part[i];
    tls += acc->tls_part[i];
    cl  += acc->clean_part[i];
    co  += acc->corr_part[i];
    cn  += acc->cnt_part[i];
  }

  uint nr = calc_nr(ep[0]);
  uint B1, needed;
  sel4096(hist1, nr, wsum, binrem, &B1, &needed);

  uint m = acc->cand_cnt; if (m > CAP) m = CAP;

  if (t == 0) tie_cnt = 0;
  // level A: bits 19:12
  hA[t] = 0;
  __syncthreads();
  for (uint i = t; i < m; i += 256) atomicAdd(&hA[(cand[i].x >> 12) & 0xFFu], 1u);
  __syncthreads();
  uint hv = hA[t];
  select256(hv, needed, wsum, binrem);
  uint A = binrem[0], rA = binrem[1];
  __syncthreads();
  hA[t] = 0;
  __syncthreads();
  // level B: bits 11:4 gated on A
  for (uint i = t; i < m; i += 256) {
    uint k = cand[i].x;
    if (((k >> 12) & 0xFFu) == A) atomicAdd(&hA[(k >> 4) & 0xFFu], 1u);
  }
  __syncthreads();
  hv = hA[t];
  select256(hv, rA, wsum, binrem);
  uint Bb = binrem[0], rB = binrem[1];
  __syncthreads();
  hA[t] = 0;
  __syncthreads();
  // level C: bits 3:0 gated on (A,Bb)
  uint pref = (A << 8) | Bb;                    // bits 19:4
  for (uint i = t; i < m; i += 256) {
    uint k = cand[i].x;
    if (((k >> 4) & 0xFFFFu) == pref) atomicAdd(&hA[k & 0xFu], 1u);
  }
  __syncthreads();
  hv = hA[t];
  select256(hv, rB, wsum, binrem);
  uint Cc = binrem[0], needT = binrem[1];
  __syncthreads();
  uint T = (B1 << 20) | (A << 12) | (Bb << 4) | Cc;
  float Tval = __uint_as_float(T);

  double cl2 = 0, co2 = 0, cn2 = 0;
  for (uint i = t; i < m; i += 256) {
    uint k = cand[i].x, ridx = cand[i].y;
    if (k < T) {
      cl2 += (double)__uint_as_float(k);
    } else if (k == T) {
      uint p = atomicAdd(&tie_cnt, 1u);
      if (p < MAXTIES) tie_idx[p] = ridx;
    } else if (mask[ridx]) {
      co2 += (double)corr[ridx]; cn2 += 1.0;
    }
  }
  __syncthreads();
  kl  = block_sum_d(kl, sred);
  tls = block_sum_d(tls, sred);
  cl  = block_sum_d(cl + cl2, sred);
  co  = block_sum_d(co + co2, sred);
  cn  = block_sum_d(cn + cn2, sred);

  if (t == 0) {
    int e = ep[0];
    if (e == 0) { out[0] = (float)(tls / (double)NROWS); return; }

    uint tc = tie_cnt; if (tc > MAXTIES) tc = MAXTIES;
    cl += (double)Tval * (double)needT;     // ties going clean (identical value)
    if (tc > needT) {
      // stable argsort tie-break by row index
      for (int a2 = 1; a2 < (int)tc; a2++) {
        uint v = tie_idx[a2];
        int b2 = a2 - 1;
        while (b2 >= 0 && tie_idx[b2] > v) { tie_idx[b2 + 1] = tie_idx[b2]; b2--; }
        tie_idx[b2 + 1] = v;
      }
      for (uint j = needT; j < tc; j++) {
        uint ridx = tie_idx[j];
        if (mask[ridx]) { co += (double)corr[ridx]; cn += 1.0; }
      }
    }
    double clean_loss = cl / (double)nr;
    double corr_mean = (cn > 0.5) ? (co / cn) : 0.0;
    double kl_mean = kl / (double)NROWS;
    out[0] = (float)(clean_loss + corr_mean + 0.1 * kl_mean);
  }
}

extern "C" void kernel_launch(void* const* d_in, const int* in_sizes, int n_in,
                              void* d_out, int out_size, void* d_ws, size_t ws_size,
                              hipStream_t stream) {
  const float* y1 = (const float*)d_in[0];
  const float* y2 = (const float*)d_in[1];
  const int* tgt = (const int*)d_in[2];
  const int* epoch = (const int*)d_in[3];
  float* out = (float*)d_out;

  float* tl = (float*)d_ws;                                   // N floats
  float* corrv = tl + NROWS;                                  // N floats
  unsigned char* mask = (unsigned char*)(corrv + NROWS);      // N bytes
  uint* hist1 = (uint*)(mask + NROWS);                        // 4096 bins
  Accum* acc = (Accum*)(hist1 + H1BINS);
  uint2* cand = (uint2*)(acc + 1);                            // CAP entries

  size_t zbytes = (size_t)H1BINS * 4 + sizeof(Accum);
  hipMemsetAsync(hist1, 0, zbytes, stream);

  k_rows<<<NROWS / 32, 256, 0, stream>>>(y1, y2, tgt, tl, corrv, mask, acc);
  k_hist1<<<NROWS / 4096, 1024, 0, stream>>>(tl, hist1);
  k_part<<<NROWS / 1024, 256, 0, stream>>>(tl, corrv, mask, hist1, epoch, acc, cand);
  k_final<<<1, 256, 0, stream>>>(corrv, mask, hist1, cand, acc, epoch, out);
}

// Round 5
// 347.830 us; speedup vs baseline: 1.0104x; 1.0104x over previous
//
#include <hip/hip_runtime.h>
#include <math.h>

#define NROWS 262144
#define NPART 1024
#define MAXTIES 256
#define H1BINS 4096
#define CAP 65536
typedef unsigned int uint;

struct Accum {
  double kl_part[NPART];
  double tls_part[NPART];
  double clean_part[NPART];
  double corr_part[NPART];
  double cnt_part[NPART];
  uint cand_cnt;
  uint pad;
};

// ============ DPP 16-lane allreduce primitives ============
// Our reduction groups are 16 CONTIGUOUS lanes = one DPP row. Allreduce over the
// 16-ring via 4 steps: xor1 (quad_perm 0xB1), xor2 (quad_perm 0x4E), row_ror:4,
// row_ror:8. Rotation-allreduce is exact for commutative+associative ops.
// DPP = full-rate VALU, ~4cy forwarding; replaces ds_swizzle (~30-40cy LDS pipe).
#define DPP_XOR1 0xB1
#define DPP_XOR2 0x4E
#define DPP_ROR4 0x124
#define DPP_ROR8 0x128

template <int CTRL>
__device__ __forceinline__ float dpp_f(float x) {
  return __int_as_float(__builtin_amdgcn_update_dpp(0, __float_as_int(x), CTRL, 0xF, 0xF, true));
}
template <int CTRL>
__device__ __forceinline__ int dpp_i(int x) {
  return __builtin_amdgcn_update_dpp(0, x, CTRL, 0xF, 0xF, true);
}

__device__ __forceinline__ float sum16(float v) {
  v += dpp_f<DPP_XOR1>(v);
  v += dpp_f<DPP_XOR2>(v);
  v += dpp_f<DPP_ROR4>(v);
  v += dpp_f<DPP_ROR8>(v);
  return v;
}

// argmax over 16 lanes: max value, min index on ties (first occurrence).
__device__ __forceinline__ void argmax16(float& m, int& i) {
#define AM_STEP(CTRL) { \
    float om = dpp_f<CTRL>(m); int oi = dpp_i<CTRL>(i); \
    if (om > m || (om == m && oi < i)) { m = om; i = oi; } }
  AM_STEP(DPP_XOR1)
  AM_STEP(DPP_XOR2)
  AM_STEP(DPP_ROR4)
  AM_STEP(DPP_ROR8)
#undef AM_STEP
}

// ============ parallel bin-select: 256 threads each hold count h; find first t with
// inclusive-prefix >= k. Unique winner: incl >= k && excl < k (h==0 can't win).
__device__ __forceinline__ void select256(uint h, uint k, uint* wsum, uint* binrem) {
  int t = threadIdx.x, l = t & 63, w = t >> 6;
  uint incl = h;
#pragma unroll
  for (int d = 1; d < 64; d <<= 1) {
    uint o = __shfl_up(incl, d, 64);
    incl += (l >= d) ? o : 0u;
  }
  if (l == 63) wsum[w] = incl;
  __syncthreads();
  uint off = 0;
#pragma unroll
  for (int i = 0; i < 3; i++) off += (i < w) ? wsum[i] : 0u;
  incl += off;
  uint excl = incl - h;
  if (incl >= k && excl < k) { binrem[0] = (uint)t; binrem[1] = k - excl; }
  __syncthreads();
}

// Find smallest bin with cumsum >= k in the 4096-bin histogram (256 chunks of 16).
__device__ __forceinline__ void sel4096(const uint* __restrict__ hist, uint k,
                                        uint* wsum, uint* binrem,
                                        uint* out_bin, uint* out_rem) {
  int t = threadIdx.x;
  const uint4* hp = reinterpret_cast<const uint4*>(hist + t * 16);
  uint4 v0 = hp[0], v1 = hp[1], v2 = hp[2], v3 = hp[3];
  uint h = v0.x + v0.y + v0.z + v0.w + v1.x + v1.y + v1.z + v1.w
         + v2.x + v2.y + v2.z + v2.w + v3.x + v3.y + v3.z + v3.w;
  select256(h, k, wsum, binrem);
  uint chunk = binrem[0], rem1 = binrem[1];
  __syncthreads();
  uint h2 = (t < 16) ? hist[chunk * 16 + t] : 0u;
  select256(h2, rem1, wsum, binrem);
  *out_bin = chunk * 16 + binrem[0];
  *out_rem = binrem[1];
  __syncthreads();
}

__device__ __forceinline__ uint calc_nr(int ep) {
  double fr = 0.005 * (double)ep; if (fr > 0.5) fr = 0.5;
  double rr = 1.0 - fr;           if (rr < 0.5) rr = 0.5;
  return (uint)(rr * (double)NROWS);
}

__device__ __forceinline__ double block_sum_d(double v, double* s) {
#pragma unroll
  for (int msk = 1; msk < 64; msk <<= 1) v += __shfl_xor(v, msk, 64);
  int wid = threadIdx.x >> 6, lane = threadIdx.x & 63;
  __syncthreads();
  if (lane == 0) s[wid] = v;
  __syncthreads();
  return s[0] + s[1] + s[2] + s[3];
}

// ============ K1: per-row stats, 16 lanes/row, 8 rows/wave (2 independent chains).
// Identical to the proven 104us version EXCEPT all 16-lane shuffle reductions are
// DPP-based (VALU pipe, ~4cy/link) instead of ds_swizzle (~30-40cy/link).
__device__ __forceinline__ void process_group(
    const float av[8], const float bv[8], int t, int row, int seg, int base,
    const float* __restrict__ y1, const float* __restrict__ y2,
    float* __restrict__ tl, float* __restrict__ corr, unsigned char* __restrict__ mask,
    float* skl, float* stt, int slot) {
  // head1 max/argmax (first occurrence)
  float m1 = av[0]; int i1 = 0;
#pragma unroll
  for (int j = 1; j < 8; j++) { if (av[j] > m1) { m1 = av[j]; i1 = j; } }
  i1 += base;
  argmax16(m1, i1);
  float m2 = bv[0]; int i2 = 0;
#pragma unroll
  for (int j = 1; j < 8; j++) { if (bv[j] > m2) { m2 = bv[j]; i2 = j; } }
  i2 += base;
  argmax16(m2, i2);
  float e1[8], e2[8];
  float z1 = 0.f, z2 = 0.f;
#pragma unroll
  for (int j = 0; j < 8; j++) { e1[j] = __expf(av[j] - m1); z1 += e1[j]; }
#pragma unroll
  for (int j = 0; j < 8; j++) { e2[j] = __expf(bv[j] - m2); z2 += e2[j]; }
  z1 = sum16(z1);
  z2 = sum16(z2);
  float logZ1 = m1 + __logf(z1), logZ2 = m2 + __logf(z2);
  float rz1 = 1.f / z1, rz2 = 1.f / z2;
  float dZ = logZ1 - logZ2;
  float kl = 0.f;
#pragma unroll
  for (int j = 0; j < 8; j++)
    kl += (e1[j] * rz1 - e2[j] * rz2) * ((av[j] - bv[j]) - dZ);
  kl = sum16(kl);

  if (seg == 0) {
    // direct cache-hot loads replace shuffle-gather loops (the lines are L1/L2 resident)
    const float* r1p = y1 + (size_t)row * 128;
    const float* r2p = y2 + (size_t)row * 128;
    float y1t = r1p[t], y2t = r2p[t], y2pl = r2p[i1];
    float total = (logZ1 - y1t) + (logZ2 - y2t);   // >= 0, so uint key order == float order
    float prod = rz1 * rz2;                        // conf1*conf2
    float corrv = sqrtf(prod) * ((logZ1 - m1) + (logZ2 - y2pl));
    tl[row] = total;
    corr[row] = corrv;
    mask[row] = (unsigned char)((i1 == i2) && (prod > 0.5f));
    skl[slot] = kl;
    stt[slot] = total;
  }
}

__global__ __launch_bounds__(256) void k_rows(
    const float* __restrict__ y1, const float* __restrict__ y2,
    const int* __restrict__ tgt,
    float* __restrict__ tl, float* __restrict__ corr, unsigned char* __restrict__ mask,
    Accum* __restrict__ acc) {
  const int tid = threadIdx.x;
  const int w = tid >> 6, l = tid & 63;
  const int wb = blockIdx.x * 32 + w * 8;          // this wave's 8 rows
  const int seg = l & 15, base = seg * 8, sub = l >> 4;

  const float4* q1 = reinterpret_cast<const float4*>(y1 + (size_t)wb * 128) + 2 * l;
  const float4* q2 = reinterpret_cast<const float4*>(y2 + (size_t)wb * 128) + 2 * l;
  // all 8 vector loads issued before any compute
  float4 a00 = q1[0],   a01 = q1[1];
  float4 a10 = q1[128], a11 = q1[129];
  float4 b00 = q2[0],   b01 = q2[1];
  float4 b10 = q2[128], b11 = q2[129];
  int r0 = wb + sub, r1 = wb + 4 + sub;
  int t0 = tgt[r0], t1 = tgt[r1];

  __shared__ float skl[32], stt[32];
  float av0[8] = {a00.x,a00.y,a00.z,a00.w,a01.x,a01.y,a01.z,a01.w};
  float bv0[8] = {b00.x,b00.y,b00.z,b00.w,b01.x,b01.y,b01.z,b01.w};
  float av1[8] = {a10.x,a10.y,a10.z,a10.w,a11.x,a11.y,a11.z,a11.w};
  float bv1[8] = {b10.x,b10.y,b10.z,b10.w,b11.x,b11.y,b11.z,b11.w};
  process_group(av0, bv0, t0, r0, seg, base, y1, y2, tl, corr, mask, skl, stt, w * 8 + sub);
  process_group(av1, bv1, t1, r1, seg, base, y1, y2, tl, corr, mask, skl, stt, w * 8 + 4 + sub);
  __syncthreads();
  if (tid == 0) {
    double sk = 0.0, st = 0.0;
#pragma unroll
    for (int i = 0; i < 32; i++) { sk += (double)skl[i]; st += (double)stt[i]; }
    int slot = blockIdx.x & (NPART - 1);
    atomicAdd(&acc->kl_part[slot], sk);
    atomicAdd(&acc->tls_part[slot], st);
  }
}

// ============ K2: level-1 histogram (top 12 bits), LDS-privatized, uint4 reads ============
__global__ __launch_bounds__(1024) void k_hist1(const float* __restrict__ tl,
                                                uint* __restrict__ hist1) {
  __shared__ uint h[H1BINS];
  int tid = threadIdx.x;
  for (int j = tid; j < H1BINS; j += 1024) h[j] = 0;
  __syncthreads();
  int i = (blockIdx.x * 1024 + tid) * 4;
  uint4 kk = *reinterpret_cast<const uint4*>(reinterpret_cast<const uint*>(tl) + i);
  atomicAdd(&h[kk.x >> 20], 1u);
  atomicAdd(&h[kk.y >> 20], 1u);
  atomicAdd(&h[kk.z >> 20], 1u);
  atomicAdd(&h[kk.w >> 20], 1u);
  __syncthreads();
  for (int j = tid; j < H1BINS; j += 1024) {
    uint v = h[j];
    if (v) atomicAdd(&hist1[j], v);
  }
}

// ============ K3: single-pass partition by 12-bit prefix.
// prefix < B1 -> clean sum; prefix > B1 -> masked corr sum; prefix == B1 -> candidate.
// Candidate append is block-aggregated: LDS staging + ONE global atomic per block.
__global__ __launch_bounds__(256) void k_part(
    const float* __restrict__ tl, const float* __restrict__ corr,
    const unsigned char* __restrict__ mask, const uint* __restrict__ hist1,
    const int* __restrict__ ep, Accum* __restrict__ acc, uint2* __restrict__ cand) {
  __shared__ uint wsum[4], binrem[2];
  __shared__ double sred[4];
  __shared__ uint lcnt, lbase;
  __shared__ uint2 lcand[1024];                 // worst case: whole block in bin B1
  uint B1, needed;
  sel4096(hist1, calc_nr(ep[0]), wsum, binrem, &B1, &needed);
  (void)needed;
  if (threadIdx.x == 0) lcnt = 0;
  __syncthreads();

  int idx = blockIdx.x * 256 + threadIdx.x;
  int i = idx * 4;
  uint4 kk = *reinterpret_cast<const uint4*>(reinterpret_cast<const uint*>(tl) + i);
  float4 cv = *reinterpret_cast<const float4*>(corr + i);
  uint mb = reinterpret_cast<const uint*>(mask)[idx];
  uint keys[4] = {kk.x, kk.y, kk.z, kk.w};
  float cvs[4] = {cv.x, cv.y, cv.z, cv.w};
  double cl = 0.0, co = 0.0, cn = 0.0;
#pragma unroll
  for (int j = 0; j < 4; j++) {
    uint pre = keys[j] >> 20;
    if (pre < B1) {
      cl += (double)__uint_as_float(keys[j]);
    } else if (pre == B1) {
      uint p = atomicAdd(&lcnt, 1u);            // LDS atomic — cheap
      lcand[p] = make_uint2(keys[j], (uint)(i + j));
    } else if ((mb >> (8 * j)) & 0xFFu) {
      co += (double)cvs[j]; cn += 1.0;
    }
  }
  __syncthreads();
  uint n = lcnt;
  if (threadIdx.x == 0 && n) lbase = atomicAdd(&acc->cand_cnt, n);
  __syncthreads();
  if (n) {
    uint b = lbase;
    for (uint j = threadIdx.x; j < n; j += 256)
      if (b + j < CAP) cand[b + j] = lcand[j];
  }
  double scl = block_sum_d(cl, sred);
  double sco = block_sum_d(co, sred);
  double scn = block_sum_d(cn, sred);
  if (threadIdx.x == 0) {
    acc->clean_part[blockIdx.x] = scl;
    acc->corr_part[blockIdx.x]  = sco;
    acc->cnt_part[blockIdx.x]   = scn;
  }
}

// ============ K4: finalize — exact select among candidates (low 20 bits via three
// LDS-histogram passes: bits 19:12, 11:4, 3:0), tie-by-row-index, combine partials.
__global__ __launch_bounds__(256) void k_final(
    const float* __restrict__ corr, const unsigned char* __restrict__ mask,
    const uint* __restrict__ hist1, const uint2* __restrict__ cand,
    Accum* __restrict__ acc, const int* __restrict__ ep, float* __restrict__ out) {
  __shared__ uint wsum[4], binrem[2];
  __shared__ double sred[4];
  __shared__ uint hA[256];
  __shared__ uint tie_idx[MAXTIES];
  __shared__ uint tie_cnt;
  int t = threadIdx.x;

  double kl = 0, tls = 0, cl = 0, co = 0, cn = 0;
  for (int i = t; i < NPART; i += 256) {
    kl  += acc->kl_part[i];
    tls += acc->tls_part[i];
    cl  += acc->clean_part[i];
    co  += acc->corr_part[i];
    cn  += acc->cnt_part[i];
  }

  uint nr = calc_nr(ep[0]);
  uint B1, needed;
  sel4096(hist1, nr, wsum, binrem, &B1, &needed);

  uint m = acc->cand_cnt; if (m > CAP) m = CAP;

  if (t == 0) tie_cnt = 0;
  // level A: bits 19:12
  hA[t] = 0;
  __syncthreads();
  for (uint i = t; i < m; i += 256) atomicAdd(&hA[(cand[i].x >> 12) & 0xFFu], 1u);
  __syncthreads();
  uint hv = hA[t];
  select256(hv, needed, wsum, binrem);
  uint A = binrem[0], rA = binrem[1];
  __syncthreads();
  hA[t] = 0;
  __syncthreads();
  // level B: bits 11:4 gated on A
  for (uint i = t; i < m; i += 256) {
    uint k = cand[i].x;
    if (((k >> 12) & 0xFFu) == A) atomicAdd(&hA[(k >> 4) & 0xFFu], 1u);
  }
  __syncthreads();
  hv = hA[t];
  select256(hv, rA, wsum, binrem);
  uint Bb = binrem[0], rB = binrem[1];
  __syncthreads();
  hA[t] = 0;
  __syncthreads();
  // level C: bits 3:0 gated on (A,Bb)
  uint pref = (A << 8) | Bb;                    // bits 19:4
  for (uint i = t; i < m; i += 256) {
    uint k = cand[i].x;
    if (((k >> 4) & 0xFFFFu) == pref) atomicAdd(&hA[k & 0xFu], 1u);
  }
  __syncthreads();
  hv = hA[t];
  select256(hv, rB, wsum, binrem);
  uint Cc = binrem[0], needT = binrem[1];
  __syncthreads();
  uint T = (B1 << 20) | (A << 12) | (Bb << 4) | Cc;
  float Tval = __uint_as_float(T);

  double cl2 = 0, co2 = 0, cn2 = 0;
  for (uint i = t; i < m; i += 256) {
    uint k = cand[i].x, ridx = cand[i].y;
    if (k < T) {
      cl2 += (double)__uint_as_float(k);
    } else if (k == T) {
      uint p = atomicAdd(&tie_cnt, 1u);
      if (p < MAXTIES) tie_idx[p] = ridx;
    } else if (mask[ridx]) {
      co2 += (double)corr[ridx]; cn2 += 1.0;
    }
  }
  __syncthreads();
  kl  = block_sum_d(kl, sred);
  tls = block_sum_d(tls, sred);
  cl  = block_sum_d(cl + cl2, sred);
  co  = block_sum_d(co + co2, sred);
  cn  = block_sum_d(cn + cn2, sred);

  if (t == 0) {
    int e = ep[0];
    if (e == 0) { out[0] = (float)(tls / (double)NROWS); return; }

    uint tc = tie_cnt; if (tc > MAXTIES) tc = MAXTIES;
    cl += (double)Tval * (double)needT;     // ties going clean (identical value)
    if (tc > needT) {
      // stable argsort tie-break by row index
      for (int a2 = 1; a2 < (int)tc; a2++) {
        uint v = tie_idx[a2];
        int b2 = a2 - 1;
        while (b2 >= 0 && tie_idx[b2] > v) { tie_idx[b2 + 1] = tie_idx[b2]; b2--; }
        tie_idx[b2 + 1] = v;
      }
      for (uint j = needT; j < tc; j++) {
        uint ridx = tie_idx[j];
        if (mask[ridx]) { co += (double)corr[ridx]; cn += 1.0; }
      }
    }
    double clean_loss = cl / (double)nr;
    double corr_mean = (cn > 0.5) ? (co / cn) : 0.0;
    double kl_mean = kl / (double)NROWS;
    out[0] = (float)(clean_loss + corr_mean + 0.1 * kl_mean);
  }
}

extern "C" void kernel_launch(void* const* d_in, const int* in_sizes, int n_in,
                              void* d_out, int out_size, void* d_ws, size_t ws_size,
                              hipStream_t stream) {
  const float* y1 = (const float*)d_in[0];
  const float* y2 = (const float*)d_in[1];
  const int* tgt = (const int*)d_in[2];
  const int* epoch = (const int*)d_in[3];
  float* out = (float*)d_out;

  float* tl = (float*)d_ws;                                   // N floats
  float* corrv = tl + NROWS;                                  // N floats
  unsigned char* mask = (unsigned char*)(corrv + NROWS);      // N bytes
  uint* hist1 = (uint*)(mask + NROWS);                        // 4096 bins
  Accum* acc = (Accum*)(hist1 + H1BINS);
  uint2* cand = (uint2*)(acc + 1);                            // CAP entries

  size_t zbytes = (size_t)H1BINS * 4 + sizeof(Accum);
  hipMemsetAsync(hist1, 0, zbytes, stream);

  k_rows<<<NROWS / 32, 256, 0, stream>>>(y1, y2, tgt, tl, corrv, mask, acc);
  k_hist1<<<NROWS / 4096, 1024, 0, stream>>>(tl, hist1);
  k_part<<<NROWS / 1024, 256, 0, stream>>>(tl, corrv, mask, hist1, epoch, acc, cand);
  k_final<<<1, 256, 0, stream>>>(corrv, mask, hist1, cand, acc, epoch, out);
}